// Round 1
// baseline (228.321 us; speedup 1.0000x reference)
//
#include <hip/hip_runtime.h>

#define SEQ 2048
#define CDIM 1024
#define NHEAD 16
#define HDIM 64

typedef __bf16 bf16x8 __attribute__((ext_vector_type(8)));
typedef float f32x4 __attribute__((ext_vector_type(4)));

typedef const __attribute__((address_space(1))) char* gcp_t;
typedef __attribute__((address_space(3))) char* lcp_t;

__device__ __forceinline__ void gload16(const void* g, void* l) {
    __builtin_amdgcn_global_load_lds((gcp_t)g, (lcp_t)l, 16, 0, 0);
}

__device__ __forceinline__ unsigned short f2bf(float f) {
    unsigned int u = __float_as_uint(f);
    u += 0x7fffu + ((u >> 16) & 1u);
    return (unsigned short)(u >> 16);
}

// ---------------- precompute kernels ----------------

__global__ void cvt_kernel(const float* __restrict__ src, unsigned short* __restrict__ dst, int n4) {
    int i = blockIdx.x * blockDim.x + threadIdx.x;
    if (i < n4) {
        float4 v = ((const float4*)src)[i];
        ushort4 o;
        o.x = f2bf(v.x); o.y = f2bf(v.y); o.z = f2bf(v.z); o.w = f2bf(v.w);
        ((ushort4*)dst)[i] = o;
    }
}

__global__ void rope_kernel(float* __restrict__ ct, float* __restrict__ st) {
    int idx = blockIdx.x * blockDim.x + threadIdx.x;  // 2048*32
    int j = idx & 31, t = idx >> 5;
    // faithful to ref: theta = 1 / 10000**(-2*(j-1)/64), all f32 roundings reproduced
    float e = -2.0f * ((float)j - 1.0f) / 64.0f;
    float denom = (float)pow(10000.0, (double)e);
    float theta = 1.0f / denom;
    float ang = (float)t * theta;
    ct[idx] = cosf(ang);
    st[idx] = sinf(ang);
}

// ---------------- GEMM (C = A * B^T), 128x128 tile, BK=32 ----------------
// MODE 0: A=x_bf16[4096][1024], B=Wqkv[3072][1024]; epilogue bias+RoPE,
//         writes q,k as [B,H,T,D] bf16 and v transposed as [B,H,D,T] bf16.
// MODE 1: A=y_bf16[4096][1024], B=Wp[1024][1024]; epilogue bias, f32 out.
template <int MODE>
__global__ __launch_bounds__(256) void gemm_bt(
    const unsigned short* __restrict__ A, const unsigned short* __restrict__ Bm,
    const float* __restrict__ b0, const float* __restrict__ b1, const float* __restrict__ b2,
    unsigned short* __restrict__ qb, unsigned short* __restrict__ kb,
    unsigned short* __restrict__ vtb, float* __restrict__ outf,
    const float* __restrict__ ctab, const float* __restrict__ stab)
{
    constexpr int K = 1024;
    __shared__ __align__(16) unsigned short As[128 * 32];
    __shared__ __align__(16) unsigned short Bs[128 * 32];
    const int tid = threadIdx.x, lane = tid & 63, wid = tid >> 6;
    const int m0 = blockIdx.y * 128, n0 = blockIdx.x * 128;
    const int wr = wid >> 1, wc = wid & 1;

    f32x4 acc[4][4] = {};

    const char* Ag = (const char*)(A + (size_t)m0 * K);
    const char* Bg = (const char*)(Bm + (size_t)n0 * K);
    const int r0 = tid >> 2, cb = (tid & 3) * 16;
    const int r1 = r0 + 64;
    const int ldsw = wid << 10;
    char* AsB = (char*)As;
    char* BsB = (char*)Bs;

    for (int k0 = 0; k0 < K; k0 += 32) {
        gload16(Ag + (size_t)r0 * 2048 + k0 * 2 + cb, AsB + ldsw);
        gload16(Ag + (size_t)r1 * 2048 + k0 * 2 + cb, AsB + 4096 + ldsw);
        gload16(Bg + (size_t)r0 * 2048 + k0 * 2 + cb, BsB + ldsw);
        gload16(Bg + (size_t)r1 * 2048 + k0 * 2 + cb, BsB + 4096 + ldsw);
        __syncthreads();
        bf16x8 af[4], bfr[4];
#pragma unroll
        for (int am = 0; am < 4; ++am)
            af[am] = *(const bf16x8*)(As + (wr * 64 + am * 16 + (lane & 15)) * 32 + (lane >> 4) * 8);
#pragma unroll
        for (int an = 0; an < 4; ++an)
            bfr[an] = *(const bf16x8*)(Bs + (wc * 64 + an * 16 + (lane & 15)) * 32 + (lane >> 4) * 8);
#pragma unroll
        for (int am = 0; am < 4; ++am)
#pragma unroll
            for (int an = 0; an < 4; ++an)
                acc[am][an] = __builtin_amdgcn_mfma_f32_16x16x32_bf16(af[am], bfr[an], acc[am][an], 0, 0, 0);
        __syncthreads();
    }

    if (MODE == 0) {
#pragma unroll
        for (int an = 0; an < 4; ++an) {
            const int ng = n0 + wc * 64 + an * 16 + (lane & 15);
            const int which = ng >> 10, nl = ng & 1023;
            const int h = nl >> 6, d = nl & 63;
            const float* bptr = (which == 0) ? b0 : (which == 1) ? b1 : b2;
            const float bias = bptr[nl];
            if (which < 2) {
                unsigned short* dst = (which == 0) ? qb : kb;
                const int j = d >> 1;
#pragma unroll
                for (int am = 0; am < 4; ++am) {
#pragma unroll
                    for (int i = 0; i < 4; ++i) {
                        const int row = m0 + wr * 64 + am * 16 + (lane >> 4) * 4 + i;
                        const int bb = row >> 11, t = row & 2047;
                        float v = acc[am][an][i] + bias;
                        float p = __shfl_xor(v, 1);
                        const float cv = ctab[t * 32 + j];
                        const float sv = stab[t * 32 + j];
                        v = (d & 1) ? fmaf(v, cv, p * sv) : fmaf(v, cv, -p * sv);
                        dst[((size_t)((bb * 16 + h) * 2048 + t)) * 64 + d] = f2bf(v);
                    }
                }
            } else {
#pragma unroll
                for (int am = 0; am < 4; ++am) {
                    const int rowb = m0 + wr * 64 + am * 16 + (lane >> 4) * 4;
                    const int bb = rowb >> 11, t = rowb & 2047;
                    ushort4 pk;
                    pk.x = f2bf(acc[am][an][0] + bias);
                    pk.y = f2bf(acc[am][an][1] + bias);
                    pk.z = f2bf(acc[am][an][2] + bias);
                    pk.w = f2bf(acc[am][an][3] + bias);
                    *(ushort4*)(vtb + ((size_t)((bb * 16 + h) * 64 + d)) * 2048 + t) = pk;
                }
            }
        }
    } else {
#pragma unroll
        for (int an = 0; an < 4; ++an) {
            const int col = n0 + wc * 64 + an * 16 + (lane & 15);
            const float bias = b0[col];
#pragma unroll
            for (int am = 0; am < 4; ++am)
#pragma unroll
                for (int i = 0; i < 4; ++i) {
                    const int row = m0 + wr * 64 + am * 16 + (lane >> 4) * 4 + i;
                    outf[(size_t)row * 1024 + col] = acc[am][an][i] + bias;
                }
        }
    }
}

// ---------------- flash attention ----------------
// grid: (16 q-tiles of 128, 32 bh). 4 waves, each owns 32 q rows.
// K staged [64 kv][64 d] and V^T staged [64 d][64 t], both XOR-swizzled via
// pre-swizzled global source (LDS dest stays linear for global_load_lds).
__global__ __launch_bounds__(256) void attn_kernel(
    const unsigned short* __restrict__ qb, const unsigned short* __restrict__ kb,
    const unsigned short* __restrict__ vtb, unsigned short* __restrict__ yb)
{
    __shared__ __align__(16) unsigned short Ks[64 * 64];
    __shared__ __align__(16) unsigned short Vs[64 * 64];
    __shared__ __align__(16) unsigned short Ps[4][32 * 64];
    const int tid = threadIdx.x, lane = tid & 63, wid = tid >> 6;
    const int bh = blockIdx.y;
    const int b = bh >> 4, h = bh & 15;
    const int q0 = blockIdx.x * 128;
    const int qw = q0 + wid * 32;
    const unsigned short* Qg = qb + (size_t)bh * SEQ * HDIM;
    const char* Kg = (const char*)(kb + (size_t)bh * SEQ * HDIM);
    const char* Vg = (const char*)(vtb + (size_t)bh * HDIM * SEQ);

    bf16x8 qf[2][2];
#pragma unroll
    for (int am = 0; am < 2; ++am)
#pragma unroll
        for (int kf = 0; kf < 2; ++kf)
            qf[am][kf] = *(const bf16x8*)(Qg + (size_t)(qw + am * 16 + (lane & 15)) * 64 + kf * 32 + (lane >> 4) * 8);

    f32x4 o[2][4] = {};
    float mrun[2][4], lrun[2][4];
#pragma unroll
    for (int am = 0; am < 2; ++am)
#pragma unroll
        for (int i = 0; i < 4; ++i) { mrun[am][i] = -3e38f; lrun[am][i] = 0.0f; }

    const int nt = (q0 >> 6) + 2;
    const int cr0 = tid >> 3, cc0 = ((tid & 7) * 16) ^ ((cr0 & 7) << 4);
    const int cr1 = cr0 + 32, cc1 = ((tid & 7) * 16) ^ ((cr1 & 7) << 4);
    const int ldsw = wid << 10;

    for (int kt = 0; kt < nt; ++kt) {
        const int kv0 = kt * 64;
        __syncthreads();
        gload16(Kg + (size_t)(kv0 + cr0) * 128 + cc0, (char*)Ks + ldsw);
        gload16(Kg + (size_t)(kv0 + cr1) * 128 + cc1, (char*)Ks + 4096 + ldsw);
        gload16(Vg + (size_t)cr0 * 4096 + kv0 * 2 + cc0, (char*)Vs + ldsw);
        gload16(Vg + (size_t)cr1 * 4096 + kv0 * 2 + cc1, (char*)Vs + 4096 + ldsw);
        __syncthreads();
        if (kv0 <= qw + 31) {
            f32x4 s[2][4] = {};
#pragma unroll
            for (int kf = 0; kf < 2; ++kf) {
                bf16x8 kfr[4];
#pragma unroll
                for (int an = 0; an < 4; ++an) {
                    const int r = an * 16 + (lane & 15);
                    kfr[an] = *(const bf16x8*)((const char*)Ks + r * 128 + ((kf * 64 + (lane >> 4) * 16) ^ ((r & 7) << 4)));
                }
#pragma unroll
                for (int am = 0; am < 2; ++am)
#pragma unroll
                    for (int an = 0; an < 4; ++an)
                        s[am][an] = __builtin_amdgcn_mfma_f32_16x16x32_bf16(qf[am][kf], kfr[an], s[am][an], 0, 0, 0);
            }
            const bool need_mask = (kv0 + 63 > qw);
#pragma unroll
            for (int am = 0; am < 2; ++am) {
#pragma unroll
                for (int i = 0; i < 4; ++i) {
                    const int q = qw + am * 16 + (lane >> 4) * 4 + i;
                    float v0 = s[am][0][i] * 0.125f, v1 = s[am][1][i] * 0.125f;
                    float v2 = s[am][2][i] * 0.125f, v3 = s[am][3][i] * 0.125f;
                    if (need_mask) {
                        const int kvl = kv0 + (lane & 15);
                        if (kvl > q) v0 = -1e30f;
                        if (kvl + 16 > q) v1 = -1e30f;
                        if (kvl + 32 > q) v2 = -1e30f;
                        if (kvl + 48 > q) v3 = -1e30f;
                    }
                    float mx = fmaxf(fmaxf(v0, v1), fmaxf(v2, v3));
                    mx = fmaxf(mx, __shfl_xor(mx, 1));
                    mx = fmaxf(mx, __shfl_xor(mx, 2));
                    mx = fmaxf(mx, __shfl_xor(mx, 4));
                    mx = fmaxf(mx, __shfl_xor(mx, 8));
                    const float mnew = fmaxf(mrun[am][i], mx);
                    const float f = __expf(mrun[am][i] - mnew);
                    const float p0 = __expf(v0 - mnew), p1 = __expf(v1 - mnew);
                    const float p2 = __expf(v2 - mnew), p3 = __expf(v3 - mnew);
                    float rs = p0 + p1 + p2 + p3;
                    rs += __shfl_xor(rs, 1); rs += __shfl_xor(rs, 2);
                    rs += __shfl_xor(rs, 4); rs += __shfl_xor(rs, 8);
                    lrun[am][i] = lrun[am][i] * f + rs;
                    mrun[am][i] = mnew;
#pragma unroll
                    for (int dn = 0; dn < 4; ++dn) o[am][dn][i] *= f;
                    const int ql = am * 16 + (lane >> 4) * 4 + i;
                    char* pbase = (char*)Ps[wid] + ql * 128;
                    const int xr = (ql & 7) << 4;
                    *(unsigned short*)(pbase + ((((lane & 15)) * 2) ^ xr)) = f2bf(p0);
                    *(unsigned short*)(pbase + ((((lane & 15) + 16) * 2) ^ xr)) = f2bf(p1);
                    *(unsigned short*)(pbase + ((((lane & 15) + 32) * 2) ^ xr)) = f2bf(p2);
                    *(unsigned short*)(pbase + ((((lane & 15) + 48) * 2) ^ xr)) = f2bf(p3);
                }
            }
#pragma unroll
            for (int kf = 0; kf < 2; ++kf) {
                bf16x8 pf[2], vf[4];
#pragma unroll
                for (int am = 0; am < 2; ++am) {
                    const int r = am * 16 + (lane & 15);
                    pf[am] = *(const bf16x8*)((const char*)Ps[wid] + r * 128 + ((kf * 64 + (lane >> 4) * 16) ^ ((r & 7) << 4)));
                }
#pragma unroll
                for (int dn = 0; dn < 4; ++dn) {
                    const int r = dn * 16 + (lane & 15);
                    vf[dn] = *(const bf16x8*)((const char*)Vs + r * 128 + ((kf * 64 + (lane >> 4) * 16) ^ ((r & 7) << 4)));
                }
#pragma unroll
                for (int am = 0; am < 2; ++am)
#pragma unroll
                    for (int dn = 0; dn < 4; ++dn)
                        o[am][dn] = __builtin_amdgcn_mfma_f32_16x16x32_bf16(pf[am], vf[dn], o[am][dn], 0, 0, 0);
            }
        }
    }
#pragma unroll
    for (int am = 0; am < 2; ++am) {
#pragma unroll
        for (int dn = 0; dn < 4; ++dn) {
            const int d = dn * 16 + (lane & 15);
#pragma unroll
            for (int i = 0; i < 4; ++i) {
                const int q = qw + am * 16 + (lane >> 4) * 4 + i;
                yb[(size_t)(b * SEQ + q) * CDIM + h * 64 + d] = f2bf(o[am][dn][i] / lrun[am][i]);
            }
        }
    }
}

// ---------------- host ----------------

extern "C" void kernel_launch(void* const* d_in, const int* in_sizes, int n_in,
                              void* d_out, int out_size, void* d_ws, size_t ws_size,
                              hipStream_t stream) {
    (void)in_sizes; (void)n_in; (void)out_size; (void)ws_size;
    const float* x  = (const float*)d_in[0];
    const float* Wq = (const float*)d_in[1];
    const float* bq = (const float*)d_in[2];
    const float* Wk = (const float*)d_in[3];
    const float* bk = (const float*)d_in[4];
    const float* Wv = (const float*)d_in[5];
    const float* bv = (const float*)d_in[6];
    const float* Wp = (const float*)d_in[7];
    const float* bp = (const float*)d_in[8];
    float* out = (float*)d_out;

    char* ws = (char*)d_ws;
    size_t off = 0;
    auto take = [&](size_t bytes) -> char* {
        char* p = ws + off;
        off = (off + bytes + 255) & ~(size_t)255;
        return p;
    };
    float* ctab = (float*)take((size_t)SEQ * 32 * 4);
    float* stab = (float*)take((size_t)SEQ * 32 * 4);
    unsigned short* xb   = (unsigned short*)take((size_t)4096 * 1024 * 2);
    unsigned short* wqkv = (unsigned short*)take((size_t)3 * 1024 * 1024 * 2);
    unsigned short* wpb  = (unsigned short*)take((size_t)1024 * 1024 * 2);
    unsigned short* qbuf = (unsigned short*)take((size_t)32 * SEQ * HDIM * 2);
    unsigned short* kbuf = (unsigned short*)take((size_t)32 * SEQ * HDIM * 2);
    unsigned short* vtb  = (unsigned short*)take((size_t)32 * HDIM * SEQ * 2);
    unsigned short* yb   = (unsigned short*)take((size_t)4096 * 1024 * 2);

    rope_kernel<<<256, 256, 0, stream>>>(ctab, stab);
    cvt_kernel<<<4096, 256, 0, stream>>>(x, xb, 1048576);
    cvt_kernel<<<1024, 256, 0, stream>>>(Wq, wqkv, 262144);
    cvt_kernel<<<1024, 256, 0, stream>>>(Wk, wqkv + 1048576, 262144);
    cvt_kernel<<<1024, 256, 0, stream>>>(Wv, wqkv + 2097152, 262144);
    cvt_kernel<<<1024, 256, 0, stream>>>(Wp, wpb, 262144);

    dim3 g0(24, 32);
    gemm_bt<0><<<g0, 256, 0, stream>>>(xb, wqkv, bq, bk, bv, qbuf, kbuf, vtb, nullptr, ctab, stab);
    dim3 g1(16, 32);
    attn_kernel<<<g1, 256, 0, stream>>>(qbuf, kbuf, vtb, yb);
    dim3 g2(8, 32);
    gemm_bt<1><<<g2, 256, 0, stream>>>(yb, wpb, bp, nullptr, nullptr, nullptr, nullptr, nullptr, out, nullptr, nullptr);
}

// Round 2
// 162.915 us; speedup vs baseline: 1.4015x; 1.4015x over previous
//
#include <hip/hip_runtime.h>

#define SEQ 2048
#define CDIM 1024
#define NHEAD 16
#define HDIM 64

typedef __bf16 bf16x8 __attribute__((ext_vector_type(8)));
typedef float f32x4 __attribute__((ext_vector_type(4)));

typedef const __attribute__((address_space(1))) char* gcp_t;
typedef __attribute__((address_space(3))) char* lcp_t;

__device__ __forceinline__ void gload16(const void* g, void* l) {
    __builtin_amdgcn_global_load_lds((gcp_t)g, (lcp_t)l, 16, 0, 0);
}

__device__ __forceinline__ unsigned short f2bf(float f) {
    unsigned int u = __float_as_uint(f);
    u += 0x7fffu + ((u >> 16) & 1u);
    return (unsigned short)(u >> 16);
}

// ---------------- precompute kernels ----------------

__global__ void cvt_kernel(const float* __restrict__ src, unsigned short* __restrict__ dst, int n4) {
    int i = blockIdx.x * blockDim.x + threadIdx.x;
    if (i < n4) {
        float4 v = ((const float4*)src)[i];
        ushort4 o;
        o.x = f2bf(v.x); o.y = f2bf(v.y); o.z = f2bf(v.z); o.w = f2bf(v.w);
        ((ushort4*)dst)[i] = o;
    }
}

// all four weight matrices in one launch
__global__ void cvtw_kernel(const float* __restrict__ Wq, const float* __restrict__ Wk,
                            const float* __restrict__ Wv, const float* __restrict__ Wp,
                            unsigned short* __restrict__ wqkv, unsigned short* __restrict__ wpb) {
    int i = blockIdx.x * blockDim.x + threadIdx.x;  // 4 * 262144 float4 groups
    int which = i >> 18, r = i & 262143;
    const float* s = (which == 0) ? Wq : (which == 1) ? Wk : (which == 2) ? Wv : Wp;
    unsigned short* d = (which < 3) ? (wqkv + (size_t)which * 1048576) : wpb;
    float4 v = ((const float4*)s)[r];
    ushort4 o;
    o.x = f2bf(v.x); o.y = f2bf(v.y); o.z = f2bf(v.z); o.w = f2bf(v.w);
    ((ushort4*)d)[r] = o;
}

__global__ void rope_kernel(float* __restrict__ ct, float* __restrict__ st) {
    int idx = blockIdx.x * blockDim.x + threadIdx.x;  // 2048*32
    int j = idx & 31, t = idx >> 5;
    // faithful to ref: theta = 1 / 10000**(-2*(j-1)/64), all f32 roundings reproduced
    float e = -2.0f * ((float)j - 1.0f) / 64.0f;
    float denom = (float)pow(10000.0, (double)e);
    float theta = 1.0f / denom;
    float ang = (float)t * theta;
    ct[idx] = cosf(ang);
    st[idx] = sinf(ang);
}

// ---------------- GEMM (C = A * B^T), 128x128 tile, BK=32 ----------------
// MODE 0: A=x_bf16[4096][1024], B=Wqkv[3072][1024]; epilogue bias+RoPE,
//         writes q (pre-scaled by 0.125*log2e) and k as [B,H,T,D] bf16,
//         v transposed as [B,H,D,T] bf16.
// MODE 1: A=y_bf16[4096][1024], B=Wp[1024][1024]; epilogue bias, f32 out.
template <int MODE>
__global__ __launch_bounds__(256) void gemm_bt(
    const unsigned short* __restrict__ A, const unsigned short* __restrict__ Bm,
    const float* __restrict__ b0, const float* __restrict__ b1, const float* __restrict__ b2,
    unsigned short* __restrict__ qb, unsigned short* __restrict__ kb,
    unsigned short* __restrict__ vtb, float* __restrict__ outf,
    const float* __restrict__ ctab, const float* __restrict__ stab)
{
    constexpr int K = 1024;
    __shared__ __align__(16) unsigned short As[128 * 32];
    __shared__ __align__(16) unsigned short Bs[128 * 32];
    const int tid = threadIdx.x, lane = tid & 63, wid = tid >> 6;
    const int m0 = blockIdx.y * 128, n0 = blockIdx.x * 128;
    const int wr = wid >> 1, wc = wid & 1;

    f32x4 acc[4][4] = {};

    const char* Ag = (const char*)(A + (size_t)m0 * K);
    const char* Bg = (const char*)(Bm + (size_t)n0 * K);
    const int r0 = tid >> 2, cb = (tid & 3) * 16;
    const int r1 = r0 + 64;
    const int ldsw = wid << 10;
    char* AsB = (char*)As;
    char* BsB = (char*)Bs;

    for (int k0 = 0; k0 < K; k0 += 32) {
        gload16(Ag + (size_t)r0 * 2048 + k0 * 2 + cb, AsB + ldsw);
        gload16(Ag + (size_t)r1 * 2048 + k0 * 2 + cb, AsB + 4096 + ldsw);
        gload16(Bg + (size_t)r0 * 2048 + k0 * 2 + cb, BsB + ldsw);
        gload16(Bg + (size_t)r1 * 2048 + k0 * 2 + cb, BsB + 4096 + ldsw);
        __syncthreads();
        bf16x8 af[4], bfr[4];
#pragma unroll
        for (int am = 0; am < 4; ++am)
            af[am] = *(const bf16x8*)(As + (wr * 64 + am * 16 + (lane & 15)) * 32 + (lane >> 4) * 8);
#pragma unroll
        for (int an = 0; an < 4; ++an)
            bfr[an] = *(const bf16x8*)(Bs + (wc * 64 + an * 16 + (lane & 15)) * 32 + (lane >> 4) * 8);
#pragma unroll
        for (int am = 0; am < 4; ++am)
#pragma unroll
            for (int an = 0; an < 4; ++an)
                acc[am][an] = __builtin_amdgcn_mfma_f32_16x16x32_bf16(af[am], bfr[an], acc[am][an], 0, 0, 0);
        __syncthreads();
    }

    if (MODE == 0) {
        const float QSCL = 0.18033688011112042f;  // 0.125 * log2(e)
#pragma unroll
        for (int an = 0; an < 4; ++an) {
            const int ng = n0 + wc * 64 + an * 16 + (lane & 15);
            const int which = ng >> 10, nl = ng & 1023;
            const int h = nl >> 6, d = nl & 63;
            const float* bptr = (which == 0) ? b0 : (which == 1) ? b1 : b2;
            const float bias = bptr[nl];
            if (which < 2) {
                unsigned short* dst = (which == 0) ? qb : kb;
                const float qs = (which == 0) ? QSCL : 1.0f;
                const int j = d >> 1;
#pragma unroll
                for (int am = 0; am < 4; ++am) {
#pragma unroll
                    for (int i = 0; i < 4; ++i) {
                        const int row = m0 + wr * 64 + am * 16 + (lane >> 4) * 4 + i;
                        const int bb = row >> 11, t = row & 2047;
                        float v = acc[am][an][i] + bias;
                        float p = __shfl_xor(v, 1);
                        const float cv = ctab[t * 32 + j];
                        const float sv = stab[t * 32 + j];
                        v = (d & 1) ? fmaf(v, cv, p * sv) : fmaf(v, cv, -p * sv);
                        dst[((size_t)((bb * 16 + h) * 2048 + t)) * 64 + d] = f2bf(v * qs);
                    }
                }
            } else {
#pragma unroll
                for (int am = 0; am < 4; ++am) {
                    const int rowb = m0 + wr * 64 + am * 16 + (lane >> 4) * 4;
                    const int bb = rowb >> 11, t = rowb & 2047;
                    ushort4 pk;
                    pk.x = f2bf(acc[am][an][0] + bias);
                    pk.y = f2bf(acc[am][an][1] + bias);
                    pk.z = f2bf(acc[am][an][2] + bias);
                    pk.w = f2bf(acc[am][an][3] + bias);
                    *(ushort4*)(vtb + ((size_t)((bb * 16 + h) * 64 + d)) * 2048 + t) = pk;
                }
            }
        }
    } else {
#pragma unroll
        for (int an = 0; an < 4; ++an) {
            const int col = n0 + wc * 64 + an * 16 + (lane & 15);
            const float bias = b0[col];
#pragma unroll
            for (int am = 0; am < 4; ++am)
#pragma unroll
                for (int i = 0; i < 4; ++i) {
                    const int row = m0 + wr * 64 + am * 16 + (lane >> 4) * 4 + i;
                    outf[(size_t)row * 1024 + col] = acc[am][an][i] + bias;
                }
        }
    }
}

// ---------------- flash attention (swapped-operand layout) ----------------
// grid: (16 q-tiles of 128, 32 bh); qtile reversed for bh>=16 so each CU's two
// resident blocks have complementary causal lengths (uniform 36 tiles/CU).
// 4 waves, each owns 32 q rows. K staged [64 kv][64 d], V^T staged [64 d][64 kv],
// double-buffered, XOR-swizzled via pre-swizzled global source.
// QK^T computed transposed: s = mfma(K, Q) -> S^T[kv][q] (col=q, lane-local kv)
// so softmax reductions are in-register trees + 2 shfls. O accumulated as
// O^T[d][q] = mfma(V^T, P^T) so rescale factor is lane-local.
__global__ __launch_bounds__(256) void attn_kernel(
    const unsigned short* __restrict__ qb, const unsigned short* __restrict__ kb,
    const unsigned short* __restrict__ vtb, unsigned short* __restrict__ yb)
{
    __shared__ __align__(16) unsigned short Ks[2][64 * 64];
    __shared__ __align__(16) unsigned short Vs[2][64 * 64];
    __shared__ __align__(16) unsigned short Ps[4][32 * 64];
    const int tid = threadIdx.x, lane = tid & 63, wid = tid >> 6;
    const int bh = blockIdx.y;
    const int b = bh >> 4, h = bh & 15;
    const int qt = (bh & 16) ? (15 - blockIdx.x) : blockIdx.x;
    const int q0 = qt * 128;
    const int qw = q0 + wid * 32;
    const unsigned short* Qg = qb + (size_t)bh * SEQ * HDIM;
    const char* Kg = (const char*)(kb + (size_t)bh * SEQ * HDIM);
    const char* Vg = (const char*)(vtb + (size_t)bh * HDIM * SEQ);

    // Q fragments (q pre-scaled by 0.125*log2e in GEMM epilogue)
    bf16x8 qf[2][2];
#pragma unroll
    for (int am = 0; am < 2; ++am)
#pragma unroll
        for (int kf = 0; kf < 2; ++kf)
            qf[am][kf] = *(const bf16x8*)(Qg + (size_t)(qw + am * 16 + (lane & 15)) * 64 + kf * 32 + (lane >> 4) * 8);

    f32x4 o[4][2] = {};              // o[dn][am] : O^T[d][q]
    float mrun[2] = {-3e38f, -3e38f};
    float lrun[2] = {0.0f, 0.0f};

    const int nt = (q0 >> 6) + 2;
    const int cr0 = tid >> 3, cc0 = ((tid & 7) * 16) ^ ((cr0 & 7) << 4);
    const int cr1 = cr0 + 32, cc1 = ((tid & 7) * 16) ^ ((cr1 & 7) << 4);
    const int ldsw = wid << 10;

    auto stage = [&](int kt, int bufi) {
        const size_t kv0 = (size_t)kt * 64;
        gload16(Kg + (kv0 + cr0) * 128 + cc0, (char*)Ks[bufi] + ldsw);
        gload16(Kg + (kv0 + cr1) * 128 + cc1, (char*)Ks[bufi] + 4096 + ldsw);
        gload16(Vg + (size_t)cr0 * 4096 + kv0 * 2 + cc0, (char*)Vs[bufi] + ldsw);
        gload16(Vg + (size_t)cr1 * 4096 + kv0 * 2 + cc1, (char*)Vs[bufi] + 4096 + ldsw);
    };

    stage(0, 0);
    __syncthreads();

    for (int kt = 0; kt < nt; ++kt) {
        const int cur = kt & 1;
        if (kt + 1 < nt) stage(kt + 1, cur ^ 1);
        const int kv0 = kt * 64;
        if (kv0 <= qw + 31) {
            // S^T tiles: s[an][am], row = kv_local = an*16+(lane>>4)*4+i, col = q
            f32x4 s[4][2] = {};
#pragma unroll
            for (int kf = 0; kf < 2; ++kf) {
                bf16x8 kfr[4];
#pragma unroll
                for (int an = 0; an < 4; ++an) {
                    const int r = an * 16 + (lane & 15);
                    kfr[an] = *(const bf16x8*)((const char*)Ks[cur] + r * 128 + ((kf * 64 + (lane >> 4) * 16) ^ ((r & 7) << 4)));
                }
#pragma unroll
                for (int an = 0; an < 4; ++an)
#pragma unroll
                    for (int am = 0; am < 2; ++am)
                        s[an][am] = __builtin_amdgcn_mfma_f32_16x16x32_bf16(kfr[an], qf[am][kf], s[an][am], 0, 0, 0);
            }
            const bool need_mask = (kv0 + 63 > qw);
#pragma unroll
            for (int am = 0; am < 2; ++am) {
                const int qg = qw + am * 16 + (lane & 15);
                const int kbase = kv0 + ((lane >> 4) << 2);
                float p[4][4];
                float mx = -3e38f;
#pragma unroll
                for (int an = 0; an < 4; ++an)
#pragma unroll
                    for (int i = 0; i < 4; ++i) {
                        float v = s[an][am][i];
                        if (need_mask && (kbase + an * 16 + i > qg)) v = -3e38f;
                        p[an][i] = v;
                        mx = fmaxf(mx, v);
                    }
                mx = fmaxf(mx, __shfl_xor(mx, 16));
                mx = fmaxf(mx, __shfl_xor(mx, 32));
                const float mnew = fmaxf(mrun[am], mx);
                const float fsc = __builtin_amdgcn_exp2f(mrun[am] - mnew);
                float rs = 0.0f;
#pragma unroll
                for (int an = 0; an < 4; ++an)
#pragma unroll
                    for (int i = 0; i < 4; ++i) {
                        p[an][i] = __builtin_amdgcn_exp2f(p[an][i] - mnew);
                        rs += p[an][i];
                    }
                rs += __shfl_xor(rs, 16);
                rs += __shfl_xor(rs, 32);
                lrun[am] = lrun[am] * fsc + rs;
                mrun[am] = mnew;
#pragma unroll
                for (int dn = 0; dn < 4; ++dn) o[dn][am] *= fsc;
                // write P[q][kv] packed (4x ds_write_b64), swizzled
                const int ql = am * 16 + (lane & 15);
                char* pb = (char*)Ps[wid] + ql * 128;
                const int xr = (ql & 7) << 4;
                const int gb = (lane >> 4) << 3;
#pragma unroll
                for (int an = 0; an < 4; ++an) {
                    ushort4 pk;
                    pk.x = f2bf(p[an][0]); pk.y = f2bf(p[an][1]);
                    pk.z = f2bf(p[an][2]); pk.w = f2bf(p[an][3]);
                    *(ushort4*)(pb + ((an * 32 + gb) ^ xr)) = pk;
                }
            }
            // PV: O^T += V^T * P^T
#pragma unroll
            for (int kf = 0; kf < 2; ++kf) {
                bf16x8 vf[4], pf[2];
#pragma unroll
                for (int dn = 0; dn < 4; ++dn) {
                    const int r = dn * 16 + (lane & 15);
                    vf[dn] = *(const bf16x8*)((const char*)Vs[cur] + r * 128 + ((kf * 64 + (lane >> 4) * 16) ^ ((r & 7) << 4)));
                }
#pragma unroll
                for (int am = 0; am < 2; ++am) {
                    const int ql = am * 16 + (lane & 15);
                    pf[am] = *(const bf16x8*)((const char*)Ps[wid] + ql * 128 + ((kf * 64 + (lane >> 4) * 16) ^ ((ql & 7) << 4)));
                }
#pragma unroll
                for (int dn = 0; dn < 4; ++dn)
#pragma unroll
                    for (int am = 0; am < 2; ++am)
                        o[dn][am] = __builtin_amdgcn_mfma_f32_16x16x32_bf16(vf[dn], pf[am], o[dn][am], 0, 0, 0);
            }
        }
        __syncthreads();
    }

#pragma unroll
    for (int am = 0; am < 2; ++am) {
        const float inv = 1.0f / lrun[am];
        const int qg = qw + am * 16 + (lane & 15);
        unsigned short* yrow = yb + (size_t)(b * SEQ + qg) * CDIM + h * 64;
#pragma unroll
        for (int dn = 0; dn < 4; ++dn) {
            const int d = dn * 16 + ((lane >> 4) << 2);
            ushort4 pk;
            pk.x = f2bf(o[dn][am][0] * inv);
            pk.y = f2bf(o[dn][am][1] * inv);
            pk.z = f2bf(o[dn][am][2] * inv);
            pk.w = f2bf(o[dn][am][3] * inv);
            *(ushort4*)(yrow + d) = pk;
        }
    }
}

// ---------------- host ----------------

extern "C" void kernel_launch(void* const* d_in, const int* in_sizes, int n_in,
                              void* d_out, int out_size, void* d_ws, size_t ws_size,
                              hipStream_t stream) {
    (void)in_sizes; (void)n_in; (void)out_size; (void)ws_size;
    const float* x  = (const float*)d_in[0];
    const float* Wq = (const float*)d_in[1];
    const float* bq = (const float*)d_in[2];
    const float* Wk = (const float*)d_in[3];
    const float* bk = (const float*)d_in[4];
    const float* Wv = (const float*)d_in[5];
    const float* bv = (const float*)d_in[6];
    const float* Wp = (const float*)d_in[7];
    const float* bp = (const float*)d_in[8];
    float* out = (float*)d_out;

    char* ws = (char*)d_ws;
    size_t off = 0;
    auto take = [&](size_t bytes) -> char* {
        char* p = ws + off;
        off = (off + bytes + 255) & ~(size_t)255;
        return p;
    };
    float* ctab = (float*)take((size_t)SEQ * 32 * 4);
    float* stab = (float*)take((size_t)SEQ * 32 * 4);
    unsigned short* xb   = (unsigned short*)take((size_t)4096 * 1024 * 2);
    unsigned short* wqkv = (unsigned short*)take((size_t)3 * 1024 * 1024 * 2);
    unsigned short* wpb  = (unsigned short*)take((size_t)1024 * 1024 * 2);
    unsigned short* qbuf = (unsigned short*)take((size_t)32 * SEQ * HDIM * 2);
    unsigned short* kbuf = (unsigned short*)take((size_t)32 * SEQ * HDIM * 2);
    unsigned short* vtb  = (unsigned short*)take((size_t)32 * HDIM * SEQ * 2);
    unsigned short* yb   = (unsigned short*)take((size_t)4096 * 1024 * 2);

    rope_kernel<<<256, 256, 0, stream>>>(ctab, stab);
    cvt_kernel<<<4096, 256, 0, stream>>>(x, xb, 1048576);
    cvtw_kernel<<<4096, 256, 0, stream>>>(Wq, Wk, Wv, Wp, wqkv, wpb);

    dim3 g0(24, 32);
    gemm_bt<0><<<g0, 256, 0, stream>>>(xb, wqkv, bq, bk, bv, qbuf, kbuf, vtb, nullptr, ctab, stab);
    dim3 g1(16, 32);
    attn_kernel<<<g1, 256, 0, stream>>>(qbuf, kbuf, vtb, yb);
    dim3 g2(8, 32);
    gemm_bt<1><<<g2, 256, 0, stream>>>(yb, wpb, bp, nullptr, nullptr, nullptr, nullptr, nullptr, out, nullptr, nullptr);
}

// Round 3
// 144.776 us; speedup vs baseline: 1.5771x; 1.1253x over previous
//
#include <hip/hip_runtime.h>

#define SEQ 2048
#define CDIM 1024
#define NHEAD 16
#define HDIM 64

typedef __bf16 bf16x8 __attribute__((ext_vector_type(8)));
typedef __bf16 bf16x4v __attribute__((ext_vector_type(4)));
typedef float f32x4 __attribute__((ext_vector_type(4)));

typedef const __attribute__((address_space(1))) char* gcp_t;
typedef __attribute__((address_space(3))) char* lcp_t;

__device__ __forceinline__ void gload16(const void* g, void* l) {
    __builtin_amdgcn_global_load_lds((gcp_t)g, (lcp_t)l, 16, 0, 0);
}

__device__ __forceinline__ unsigned short f2bf(float f) {
    unsigned int u = __float_as_uint(f);
    u += 0x7fffu + ((u >> 16) & 1u);
    return (unsigned short)(u >> 16);
}

// ---------------- precompute kernels ----------------

__global__ void cvt_kernel(const float* __restrict__ src, unsigned short* __restrict__ dst, int n4) {
    int i = blockIdx.x * blockDim.x + threadIdx.x;
    if (i < n4) {
        float4 v = ((const float4*)src)[i];
        ushort4 o;
        o.x = f2bf(v.x); o.y = f2bf(v.y); o.z = f2bf(v.z); o.w = f2bf(v.w);
        ((ushort4*)dst)[i] = o;
    }
}

// all four weight matrices in one launch
__global__ void cvtw_kernel(const float* __restrict__ Wq, const float* __restrict__ Wk,
                            const float* __restrict__ Wv, const float* __restrict__ Wp,
                            unsigned short* __restrict__ wqkv, unsigned short* __restrict__ wpb) {
    int i = blockIdx.x * blockDim.x + threadIdx.x;  // 4 * 262144 float4 groups
    int which = i >> 18, r = i & 262143;
    const float* s = (which == 0) ? Wq : (which == 1) ? Wk : (which == 2) ? Wv : Wp;
    unsigned short* d = (which < 3) ? (wqkv + (size_t)which * 1048576) : wpb;
    float4 v = ((const float4*)s)[r];
    ushort4 o;
    o.x = f2bf(v.x); o.y = f2bf(v.y); o.z = f2bf(v.z); o.w = f2bf(v.w);
    ((ushort4*)d)[r] = o;
}

__global__ void rope_kernel(float* __restrict__ ct, float* __restrict__ st) {
    int idx = blockIdx.x * blockDim.x + threadIdx.x;  // 2048*32
    int j = idx & 31, t = idx >> 5;
    // faithful to ref: theta = 1 / 10000**(-2*(j-1)/64), all f32 roundings reproduced
    float e = -2.0f * ((float)j - 1.0f) / 64.0f;
    float denom = (float)pow(10000.0, (double)e);
    float theta = 1.0f / denom;
    float ang = (float)t * theta;
    ct[idx] = cosf(ang);
    st[idx] = sinf(ang);
}

// ---------------- GEMM (C = A * B^T), 128x128 tile, BK=32 ----------------
// MODE 0: A=x_bf16[4096][1024], B=Wqkv[3072][1024]; epilogue bias+RoPE,
//         writes q (pre-scaled by 0.125*log2e) and k as [B,H,T,D] bf16,
//         v transposed as [B,H,D,T] bf16.
// MODE 1: A=y_bf16[4096][1024], B=Wp[1024][1024]; epilogue bias, f32 out.
template <int MODE>
__global__ __launch_bounds__(256) void gemm_bt(
    const unsigned short* __restrict__ A, const unsigned short* __restrict__ Bm,
    const float* __restrict__ b0, const float* __restrict__ b1, const float* __restrict__ b2,
    unsigned short* __restrict__ qb, unsigned short* __restrict__ kb,
    unsigned short* __restrict__ vtb, float* __restrict__ outf,
    const float* __restrict__ ctab, const float* __restrict__ stab)
{
    constexpr int K = 1024;
    __shared__ __align__(16) unsigned short As[128 * 32];
    __shared__ __align__(16) unsigned short Bs[128 * 32];
    const int tid = threadIdx.x, lane = tid & 63, wid = tid >> 6;
    const int m0 = blockIdx.y * 128, n0 = blockIdx.x * 128;
    const int wr = wid >> 1, wc = wid & 1;

    f32x4 acc[4][4] = {};

    const char* Ag = (const char*)(A + (size_t)m0 * K);
    const char* Bg = (const char*)(Bm + (size_t)n0 * K);
    const int r0 = tid >> 2, cb = (tid & 3) * 16;
    const int r1 = r0 + 64;
    const int ldsw = wid << 10;
    char* AsB = (char*)As;
    char* BsB = (char*)Bs;

    for (int k0 = 0; k0 < K; k0 += 32) {
        gload16(Ag + (size_t)r0 * 2048 + k0 * 2 + cb, AsB + ldsw);
        gload16(Ag + (size_t)r1 * 2048 + k0 * 2 + cb, AsB + 4096 + ldsw);
        gload16(Bg + (size_t)r0 * 2048 + k0 * 2 + cb, BsB + ldsw);
        gload16(Bg + (size_t)r1 * 2048 + k0 * 2 + cb, BsB + 4096 + ldsw);
        __syncthreads();
        bf16x8 af[4], bfr[4];
#pragma unroll
        for (int am = 0; am < 4; ++am)
            af[am] = *(const bf16x8*)(As + (wr * 64 + am * 16 + (lane & 15)) * 32 + (lane >> 4) * 8);
#pragma unroll
        for (int an = 0; an < 4; ++an)
            bfr[an] = *(const bf16x8*)(Bs + (wc * 64 + an * 16 + (lane & 15)) * 32 + (lane >> 4) * 8);
#pragma unroll
        for (int am = 0; am < 4; ++am)
#pragma unroll
            for (int an = 0; an < 4; ++an)
                acc[am][an] = __builtin_amdgcn_mfma_f32_16x16x32_bf16(af[am], bfr[an], acc[am][an], 0, 0, 0);
        __syncthreads();
    }

    if (MODE == 0) {
        const float QSCL = 0.18033688011112042f;  // 0.125 * log2(e)
#pragma unroll
        for (int an = 0; an < 4; ++an) {
            const int ng = n0 + wc * 64 + an * 16 + (lane & 15);
            const int which = ng >> 10, nl = ng & 1023;
            const int h = nl >> 6, d = nl & 63;
            const float* bptr = (which == 0) ? b0 : (which == 1) ? b1 : b2;
            const float bias = bptr[nl];
            if (which < 2) {
                unsigned short* dst = (which == 0) ? qb : kb;
                const float qs = (which == 0) ? QSCL : 1.0f;
                const int j = d >> 1;
#pragma unroll
                for (int am = 0; am < 4; ++am) {
#pragma unroll
                    for (int i = 0; i < 4; ++i) {
                        const int row = m0 + wr * 64 + am * 16 + (lane >> 4) * 4 + i;
                        const int bb = row >> 11, t = row & 2047;
                        float v = acc[am][an][i] + bias;
                        float p = __shfl_xor(v, 1);
                        const float cv = ctab[t * 32 + j];
                        const float sv = stab[t * 32 + j];
                        v = (d & 1) ? fmaf(v, cv, p * sv) : fmaf(v, cv, -p * sv);
                        dst[((size_t)((bb * 16 + h) * 2048 + t)) * 64 + d] = f2bf(v * qs);
                    }
                }
            } else {
#pragma unroll
                for (int am = 0; am < 4; ++am) {
                    const int rowb = m0 + wr * 64 + am * 16 + (lane >> 4) * 4;
                    const int bb = rowb >> 11, t = rowb & 2047;
                    ushort4 pk;
                    pk.x = f2bf(acc[am][an][0] + bias);
                    pk.y = f2bf(acc[am][an][1] + bias);
                    pk.z = f2bf(acc[am][an][2] + bias);
                    pk.w = f2bf(acc[am][an][3] + bias);
                    *(ushort4*)(vtb + ((size_t)((bb * 16 + h) * 64 + d)) * 2048 + t) = pk;
                }
            }
        }
    } else {
#pragma unroll
        for (int an = 0; an < 4; ++an) {
            const int col = n0 + wc * 64 + an * 16 + (lane & 15);
            const float bias = b0[col];
#pragma unroll
            for (int am = 0; am < 4; ++am)
#pragma unroll
                for (int i = 0; i < 4; ++i) {
                    const int row = m0 + wr * 64 + am * 16 + (lane >> 4) * 4 + i;
                    outf[(size_t)row * 1024 + col] = acc[am][an][i] + bias;
                }
        }
    }
}

// ---------------- flash attention (swapped-operand layout) ----------------
// grid: (32 q-tiles of 64, 32 bh); qtile reversed for bh>=16 so each CU's four
// resident blocks have complementary causal lengths (uniform 66 tiles/CU).
// 4 waves, each owns 16 q rows. K staged [64 kv][64 d], V^T staged [64 d][64 kv],
// double-buffered, XOR-swizzled via pre-swizzled global source. LDS 40KB ->
// 4 blocks/CU (16 waves).
// QK^T computed transposed: s = mfma(K, Q) -> S^T[kv][q] (col=q, lane-local kv)
// so softmax reductions are in-register trees + 2 shfls. O accumulated as
// O^T[d][q] = mfma(V^T, P^T) so rescale factor is lane-local.
__global__ __launch_bounds__(256) void attn_kernel(
    const unsigned short* __restrict__ qb, const unsigned short* __restrict__ kb,
    const unsigned short* __restrict__ vtb, unsigned short* __restrict__ yb)
{
    __shared__ __align__(16) unsigned short Ks[2][64 * 64];
    __shared__ __align__(16) unsigned short Vs[2][64 * 64];
    __shared__ __align__(16) unsigned short Ps[4][16 * 64];
    const int tid = threadIdx.x, lane = tid & 63, wid = tid >> 6;
    const int bh = blockIdx.y;
    const int b = bh >> 4, h = bh & 15;
    const int qt = (bh & 16) ? (31 - blockIdx.x) : blockIdx.x;
    const int q0 = qt * 64;
    const int qw = q0 + wid * 16;
    const unsigned short* Qg = qb + (size_t)bh * SEQ * HDIM;
    const char* Kg = (const char*)(kb + (size_t)bh * SEQ * HDIM);
    const char* Vg = (const char*)(vtb + (size_t)bh * HDIM * SEQ);

    // Q fragments (q pre-scaled by 0.125*log2e in GEMM epilogue)
    bf16x8 qf[2];
#pragma unroll
    for (int kf = 0; kf < 2; ++kf)
        qf[kf] = *(const bf16x8*)(Qg + (size_t)(qw + (lane & 15)) * 64 + kf * 32 + (lane >> 4) * 8);

    f32x4 o[4] = {};                 // o[dn] : O^T[d][q]
    float mrun = -3e38f;
    float lrun = 0.0f;

    const int nt = qt + 1;
    const int cr0 = tid >> 3, cc0 = ((tid & 7) * 16) ^ ((cr0 & 7) << 4);
    const int cr1 = cr0 + 32, cc1 = ((tid & 7) * 16) ^ ((cr1 & 7) << 4);
    const int ldsw = wid << 10;

    auto stage = [&](int kt, int bufi) {
        const size_t kv0 = (size_t)kt * 64;
        gload16(Kg + (kv0 + cr0) * 128 + cc0, (char*)Ks[bufi] + ldsw);
        gload16(Kg + (kv0 + cr1) * 128 + cc1, (char*)Ks[bufi] + 4096 + ldsw);
        gload16(Vg + (size_t)cr0 * 4096 + kv0 * 2 + cc0, (char*)Vs[bufi] + ldsw);
        gload16(Vg + (size_t)cr1 * 4096 + kv0 * 2 + cc1, (char*)Vs[bufi] + 4096 + ldsw);
    };

    stage(0, 0);
    __syncthreads();

    for (int kt = 0; kt < nt; ++kt) {
        const int cur = kt & 1;
        if (kt + 1 < nt) stage(kt + 1, cur ^ 1);
        const int kv0 = kt * 64;
        {
            // S^T tiles: s[an], row = kv_local = an*16+(lane>>4)*4+i, col = q
            f32x4 s[4] = {};
            __builtin_amdgcn_s_setprio(1);
#pragma unroll
            for (int kf = 0; kf < 2; ++kf) {
                bf16x8 kfr[4];
#pragma unroll
                for (int an = 0; an < 4; ++an) {
                    const int r = an * 16 + (lane & 15);
                    kfr[an] = *(const bf16x8*)((const char*)Ks[cur] + r * 128 + ((kf * 64 + (lane >> 4) * 16) ^ ((r & 7) << 4)));
                }
#pragma unroll
                for (int an = 0; an < 4; ++an)
                    s[an] = __builtin_amdgcn_mfma_f32_16x16x32_bf16(kfr[an], qf[kf], s[an], 0, 0, 0);
            }
            __builtin_amdgcn_s_setprio(0);
            const bool need_mask = (kv0 + 63 > qw);
            const int qg = qw + (lane & 15);
            const int kbase = kv0 + ((lane >> 4) << 2);
            float p[4][4];
            float mx = -3e38f;
#pragma unroll
            for (int an = 0; an < 4; ++an)
#pragma unroll
                for (int i = 0; i < 4; ++i) {
                    float v = s[an][i];
                    if (need_mask && (kbase + an * 16 + i > qg)) v = -3e38f;
                    p[an][i] = v;
                    mx = fmaxf(mx, v);
                }
            mx = fmaxf(mx, __shfl_xor(mx, 16));
            mx = fmaxf(mx, __shfl_xor(mx, 32));
            // defer-max (T13): only rescale when max grew by > 8 (log2 units)
            if (!__all(mx <= mrun + 8.0f)) {
                const float mnew = fmaxf(mrun, mx);
                const float fsc = __builtin_amdgcn_exp2f(mrun - mnew);
                lrun *= fsc;
#pragma unroll
                for (int dn = 0; dn < 4; ++dn) o[dn] *= fsc;
                mrun = mnew;
            }
            float rs = 0.0f;
#pragma unroll
            for (int an = 0; an < 4; ++an)
#pragma unroll
                for (int i = 0; i < 4; ++i) {
                    p[an][i] = __builtin_amdgcn_exp2f(p[an][i] - mrun);
                    rs += p[an][i];
                }
            rs += __shfl_xor(rs, 16);
            rs += __shfl_xor(rs, 32);
            lrun += rs;
            // write P[q][kv] packed (4x ds_write_b64), swizzled
            const int ql = lane & 15;
            char* pb = (char*)Ps[wid] + ql * 128;
            const int xr = (ql & 7) << 4;
            const int gb = (lane >> 4) << 3;
#pragma unroll
            for (int an = 0; an < 4; ++an) {
                bf16x4v pk;
                pk[0] = (__bf16)p[an][0]; pk[1] = (__bf16)p[an][1];
                pk[2] = (__bf16)p[an][2]; pk[3] = (__bf16)p[an][3];
                *(bf16x4v*)(pb + ((an * 32 + gb) ^ xr)) = pk;
            }
            // PV: O^T += V^T * P^T
            __builtin_amdgcn_s_setprio(1);
#pragma unroll
            for (int kf = 0; kf < 2; ++kf) {
                bf16x8 vf[4], pf;
#pragma unroll
                for (int dn = 0; dn < 4; ++dn) {
                    const int r = dn * 16 + (lane & 15);
                    vf[dn] = *(const bf16x8*)((const char*)Vs[cur] + r * 128 + ((kf * 64 + (lane >> 4) * 16) ^ ((r & 7) << 4)));
                }
                {
                    const int qlr = lane & 15;
                    pf = *(const bf16x8*)((const char*)Ps[wid] + qlr * 128 + ((kf * 64 + (lane >> 4) * 16) ^ ((qlr & 7) << 4)));
                }
#pragma unroll
                for (int dn = 0; dn < 4; ++dn)
                    o[dn] = __builtin_amdgcn_mfma_f32_16x16x32_bf16(vf[dn], pf, o[dn], 0, 0, 0);
            }
            __builtin_amdgcn_s_setprio(0);
        }
        __syncthreads();
    }

    {
        const float inv = 1.0f / lrun;
        const int qg = qw + (lane & 15);
        unsigned short* yrow = yb + (size_t)(b * SEQ + qg) * CDIM + h * 64;
#pragma unroll
        for (int dn = 0; dn < 4; ++dn) {
            const int d = dn * 16 + ((lane >> 4) << 2);
            bf16x4v pk;
            pk[0] = (__bf16)(o[dn][0] * inv);
            pk[1] = (__bf16)(o[dn][1] * inv);
            pk[2] = (__bf16)(o[dn][2] * inv);
            pk[3] = (__bf16)(o[dn][3] * inv);
            *(bf16x4v*)(yrow + d) = pk;
        }
    }
}

// ---------------- host ----------------

extern "C" void kernel_launch(void* const* d_in, const int* in_sizes, int n_in,
                              void* d_out, int out_size, void* d_ws, size_t ws_size,
                              hipStream_t stream) {
    (void)in_sizes; (void)n_in; (void)out_size; (void)ws_size;
    const float* x  = (const float*)d_in[0];
    const float* Wq = (const float*)d_in[1];
    const float* bq = (const float*)d_in[2];
    const float* Wk = (const float*)d_in[3];
    const float* bk = (const float*)d_in[4];
    const float* Wv = (const float*)d_in[5];
    const float* bv = (const float*)d_in[6];
    const float* Wp = (const float*)d_in[7];
    const float* bp = (const float*)d_in[8];
    float* out = (float*)d_out;

    char* ws = (char*)d_ws;
    size_t off = 0;
    auto take = [&](size_t bytes) -> char* {
        char* p = ws + off;
        off = (off + bytes + 255) & ~(size_t)255;
        return p;
    };
    float* ctab = (float*)take((size_t)SEQ * 32 * 4);
    float* stab = (float*)take((size_t)SEQ * 32 * 4);
    unsigned short* xb   = (unsigned short*)take((size_t)4096 * 1024 * 2);
    unsigned short* wqkv = (unsigned short*)take((size_t)3 * 1024 * 1024 * 2);
    unsigned short* wpb  = (unsigned short*)take((size_t)1024 * 1024 * 2);
    unsigned short* qbuf = (unsigned short*)take((size_t)32 * SEQ * HDIM * 2);
    unsigned short* kbuf = (unsigned short*)take((size_t)32 * SEQ * HDIM * 2);
    unsigned short* vtb  = (unsigned short*)take((size_t)32 * HDIM * SEQ * 2);
    unsigned short* yb   = (unsigned short*)take((size_t)4096 * 1024 * 2);

    rope_kernel<<<256, 256, 0, stream>>>(ctab, stab);
    cvt_kernel<<<4096, 256, 0, stream>>>(x, xb, 1048576);
    cvtw_kernel<<<4096, 256, 0, stream>>>(Wq, Wk, Wv, Wp, wqkv, wpb);

    dim3 g0(24, 32);
    gemm_bt<0><<<g0, 256, 0, stream>>>(xb, wqkv, bq, bk, bv, qbuf, kbuf, vtb, nullptr, ctab, stab);
    dim3 g1(32, 32);
    attn_kernel<<<g1, 256, 0, stream>>>(qbuf, kbuf, vtb, yb);
    dim3 g2(8, 32);
    gemm_bt<1><<<g2, 256, 0, stream>>>(yb, wpb, bp, nullptr, nullptr, nullptr, nullptr, nullptr, out, nullptr, nullptr);
}

// Round 4
// 139.468 us; speedup vs baseline: 1.6371x; 1.0381x over previous
//
#include <hip/hip_runtime.h>

#define SEQ 2048
#define CDIM 1024
#define NHEAD 16
#define HDIM 64

typedef __bf16 bf16x8 __attribute__((ext_vector_type(8)));
typedef __bf16 bf16x4v __attribute__((ext_vector_type(4)));
typedef float f32x4 __attribute__((ext_vector_type(4)));

typedef const __attribute__((address_space(1))) char* gcp_t;
typedef __attribute__((address_space(3))) char* lcp_t;

__device__ __forceinline__ void gload16(const void* g, void* l) {
    __builtin_amdgcn_global_load_lds((gcp_t)g, (lcp_t)l, 16, 0, 0);
}

__device__ __forceinline__ unsigned short f2bf(float f) {
    unsigned int u = __float_as_uint(f);
    u += 0x7fffu + ((u >> 16) & 1u);
    return (unsigned short)(u >> 16);
}

// ---------------- precompute kernels ----------------

__global__ void cvt_kernel(const float* __restrict__ src, unsigned short* __restrict__ dst, int n4) {
    int i = blockIdx.x * blockDim.x + threadIdx.x;
    if (i < n4) {
        float4 v = ((const float4*)src)[i];
        ushort4 o;
        o.x = f2bf(v.x); o.y = f2bf(v.y); o.z = f2bf(v.z); o.w = f2bf(v.w);
        ((ushort4*)dst)[i] = o;
    }
}

// all four weight matrices in one launch
__global__ void cvtw_kernel(const float* __restrict__ Wq, const float* __restrict__ Wk,
                            const float* __restrict__ Wv, const float* __restrict__ Wp,
                            unsigned short* __restrict__ wqkv, unsigned short* __restrict__ wpb) {
    int i = blockIdx.x * blockDim.x + threadIdx.x;  // 4 * 262144 float4 groups
    int which = i >> 18, r = i & 262143;
    const float* s = (which == 0) ? Wq : (which == 1) ? Wk : (which == 2) ? Wv : Wp;
    unsigned short* d = (which < 3) ? (wqkv + (size_t)which * 1048576) : wpb;
    float4 v = ((const float4*)s)[r];
    ushort4 o;
    o.x = f2bf(v.x); o.y = f2bf(v.y); o.z = f2bf(v.z); o.w = f2bf(v.w);
    ((ushort4*)d)[r] = o;
}

// interleaved (cos,sin) table: cstab[t*32+j] = {cos, sin}
__global__ void rope_kernel(float2* __restrict__ cstab) {
    int idx = blockIdx.x * blockDim.x + threadIdx.x;  // 2048*32
    int j = idx & 31, t = idx >> 5;
    // faithful to ref: theta = 1 / 10000**(-2*(j-1)/64), all f32 roundings reproduced
    float e = -2.0f * ((float)j - 1.0f) / 64.0f;
    float denom = (float)pow(10000.0, (double)e);
    float theta = 1.0f / denom;
    float ang = (float)t * theta;
    cstab[idx] = make_float2(cosf(ang), sinf(ang));
}

// ---------------- GEMM (C = A * B^T), 128x128 tile, BK=32, 2-phase dbuf ----
// MODE 0: A=x_bf16[4096][1024], B=Wqkv[3072][1024]; epilogue bias+RoPE,
//         writes q (pre-scaled by 0.125*log2e) and k as [B,H,T,D] bf16,
//         v transposed as [B,H,D,T] bf16.
// MODE 1: A=y_bf16[4096][1024], B=Wp[1024][1024]; epilogue bias, f32 out.
template <int MODE>
__global__ __launch_bounds__(256) void gemm_bt(
    const unsigned short* __restrict__ A, const unsigned short* __restrict__ Bm,
    const float* __restrict__ b0, const float* __restrict__ b1, const float* __restrict__ b2,
    unsigned short* __restrict__ qb, unsigned short* __restrict__ kb,
    unsigned short* __restrict__ vtb, float* __restrict__ outf,
    const float2* __restrict__ cstab)
{
    constexpr int K = 1024;
    constexpr int NIT = K / 32;
    __shared__ __align__(16) unsigned short As[2][128 * 32];
    __shared__ __align__(16) unsigned short Bs[2][128 * 32];
    const int tid = threadIdx.x, lane = tid & 63, wid = tid >> 6;
    const int m0 = blockIdx.y * 128, n0 = blockIdx.x * 128;
    const int wr = wid >> 1, wc = wid & 1;

    f32x4 acc[4][4] = {};

    const char* Ag = (const char*)(A + (size_t)m0 * K);
    const char* Bg = (const char*)(Bm + (size_t)n0 * K);
    const int r0 = tid >> 2, cb = (tid & 3) * 16;
    const int r1 = r0 + 64;
    const int ldsw = wid << 10;

    auto stage = [&](int k0, int bufi) {
        gload16(Ag + (size_t)r0 * 2048 + k0 * 2 + cb, (char*)As[bufi] + ldsw);
        gload16(Ag + (size_t)r1 * 2048 + k0 * 2 + cb, (char*)As[bufi] + 4096 + ldsw);
        gload16(Bg + (size_t)r0 * 2048 + k0 * 2 + cb, (char*)Bs[bufi] + ldsw);
        gload16(Bg + (size_t)r1 * 2048 + k0 * 2 + cb, (char*)Bs[bufi] + 4096 + ldsw);
    };

    stage(0, 0);
    __syncthreads();

    for (int it = 0; it < NIT; ++it) {
        const int cur = it & 1;
        if (it + 1 < NIT) stage((it + 1) * 32, cur ^ 1);
        bf16x8 af[4], bfr[4];
#pragma unroll
        for (int am = 0; am < 4; ++am)
            af[am] = *(const bf16x8*)(As[cur] + (wr * 64 + am * 16 + (lane & 15)) * 32 + (lane >> 4) * 8);
#pragma unroll
        for (int an = 0; an < 4; ++an)
            bfr[an] = *(const bf16x8*)(Bs[cur] + (wc * 64 + an * 16 + (lane & 15)) * 32 + (lane >> 4) * 8);
#pragma unroll
        for (int am = 0; am < 4; ++am)
#pragma unroll
            for (int an = 0; an < 4; ++an)
                acc[am][an] = __builtin_amdgcn_mfma_f32_16x16x32_bf16(af[am], bfr[an], acc[am][an], 0, 0, 0);
        __syncthreads();
    }

    if (MODE == 0) {
        const float QSCL = 0.18033688011112042f;  // 0.125 * log2(e)
#pragma unroll
        for (int an = 0; an < 4; ++an) {
            const int ng = n0 + wc * 64 + an * 16 + (lane & 15);
            const int which = ng >> 10, nl = ng & 1023;
            const int h = nl >> 6, d = nl & 63;
            const float* bptr = (which == 0) ? b0 : (which == 1) ? b1 : b2;
            const float bias = bptr[nl];
            if (which < 2) {
                unsigned short* dst = (which == 0) ? qb : kb;
                const float qs = (which == 0) ? QSCL : 1.0f;
                const int j = d >> 1;
#pragma unroll
                for (int am = 0; am < 4; ++am) {
#pragma unroll
                    for (int i = 0; i < 4; ++i) {
                        const int row = m0 + wr * 64 + am * 16 + (lane >> 4) * 4 + i;
                        const int bb = row >> 11, t = row & 2047;
                        float v = acc[am][an][i] + bias;
                        float p = __shfl_xor(v, 1);
                        const float2 cs = cstab[t * 32 + j];
                        v = (d & 1) ? fmaf(v, cs.x, p * cs.y) : fmaf(v, cs.x, -p * cs.y);
                        dst[((size_t)((bb * 16 + h) * 2048 + t)) * 64 + d] = f2bf(v * qs);
                    }
                }
            } else {
#pragma unroll
                for (int am = 0; am < 4; ++am) {
                    const int rowb = m0 + wr * 64 + am * 16 + (lane >> 4) * 4;
                    const int bb = rowb >> 11, t = rowb & 2047;
                    ushort4 pk;
                    pk.x = f2bf(acc[am][an][0] + bias);
                    pk.y = f2bf(acc[am][an][1] + bias);
                    pk.z = f2bf(acc[am][an][2] + bias);
                    pk.w = f2bf(acc[am][an][3] + bias);
                    *(ushort4*)(vtb + ((size_t)((bb * 16 + h) * 64 + d)) * 2048 + t) = pk;
                }
            }
        }
    } else {
#pragma unroll
        for (int an = 0; an < 4; ++an) {
            const int col = n0 + wc * 64 + an * 16 + (lane & 15);
            const float bias = b0[col];
#pragma unroll
            for (int am = 0; am < 4; ++am)
#pragma unroll
                for (int i = 0; i < 4; ++i) {
                    const int row = m0 + wr * 64 + am * 16 + (lane >> 4) * 4 + i;
                    outf[(size_t)row * 1024 + col] = acc[am][an][i] + bias;
                }
        }
    }
}

// ---------------- flash attention (swapped-operand layout) ----------------
// grid: (32 q-tiles of 64, 32 bh); qtile reversed for bh>=16 so each CU's four
// resident blocks have complementary causal lengths (uniform 66 tiles/CU).
// 4 waves, each owns 16 q rows. K staged [64 kv][64 d], V^T staged [64 d][64 kv],
// double-buffered, XOR-swizzled via pre-swizzled global source. LDS 40KB ->
// 4 blocks/CU (16 waves).
// QK^T computed transposed: s = mfma(K, Q) -> S^T[kv][q] (col=q, lane-local kv)
// so softmax reductions are in-register trees + 2 shfls. O accumulated as
// O^T[d][q] = mfma(V^T, P^T) so rescale factor is lane-local.
__global__ __launch_bounds__(256) void attn_kernel(
    const unsigned short* __restrict__ qb, const unsigned short* __restrict__ kb,
    const unsigned short* __restrict__ vtb, unsigned short* __restrict__ yb)
{
    __shared__ __align__(16) unsigned short Ks[2][64 * 64];
    __shared__ __align__(16) unsigned short Vs[2][64 * 64];
    __shared__ __align__(16) unsigned short Ps[4][16 * 64];
    const int tid = threadIdx.x, lane = tid & 63, wid = tid >> 6;
    const int bh = blockIdx.y;
    const int b = bh >> 4, h = bh & 15;
    const int qt = (bh & 16) ? (31 - blockIdx.x) : blockIdx.x;
    const int q0 = qt * 64;
    const int qw = q0 + wid * 16;
    const unsigned short* Qg = qb + (size_t)bh * SEQ * HDIM;
    const char* Kg = (const char*)(kb + (size_t)bh * SEQ * HDIM);
    const char* Vg = (const char*)(vtb + (size_t)bh * HDIM * SEQ);

    // Q fragments (q pre-scaled by 0.125*log2e in GEMM epilogue)
    bf16x8 qf[2];
#pragma unroll
    for (int kf = 0; kf < 2; ++kf)
        qf[kf] = *(const bf16x8*)(Qg + (size_t)(qw + (lane & 15)) * 64 + kf * 32 + (lane >> 4) * 8);

    f32x4 o[4] = {};                 // o[dn] : O^T[d][q]
    float mrun = -3e38f;
    float lrun = 0.0f;

    const int nt = qt + 1;
    const int cr0 = tid >> 3, cc0 = ((tid & 7) * 16) ^ ((cr0 & 7) << 4);
    const int cr1 = cr0 + 32, cc1 = ((tid & 7) * 16) ^ ((cr1 & 7) << 4);
    const int ldsw = wid << 10;

    auto stage = [&](int kt, int bufi) {
        const size_t kv0 = (size_t)kt * 64;
        gload16(Kg + (kv0 + cr0) * 128 + cc0, (char*)Ks[bufi] + ldsw);
        gload16(Kg + (kv0 + cr1) * 128 + cc1, (char*)Ks[bufi] + 4096 + ldsw);
        gload16(Vg + (size_t)cr0 * 4096 + kv0 * 2 + cc0, (char*)Vs[bufi] + ldsw);
        gload16(Vg + (size_t)cr1 * 4096 + kv0 * 2 + cc1, (char*)Vs[bufi] + 4096 + ldsw);
    };

    stage(0, 0);
    __syncthreads();

    for (int kt = 0; kt < nt; ++kt) {
        const int cur = kt & 1;
        if (kt + 1 < nt) stage(kt + 1, cur ^ 1);
        const int kv0 = kt * 64;
        {
            // S^T tiles: s[an], row = kv_local = an*16+(lane>>4)*4+i, col = q
            f32x4 s[4] = {};
            __builtin_amdgcn_s_setprio(1);
#pragma unroll
            for (int kf = 0; kf < 2; ++kf) {
                bf16x8 kfr[4];
#pragma unroll
                for (int an = 0; an < 4; ++an) {
                    const int r = an * 16 + (lane & 15);
                    kfr[an] = *(const bf16x8*)((const char*)Ks[cur] + r * 128 + ((kf * 64 + (lane >> 4) * 16) ^ ((r & 7) << 4)));
                }
#pragma unroll
                for (int an = 0; an < 4; ++an)
                    s[an] = __builtin_amdgcn_mfma_f32_16x16x32_bf16(kfr[an], qf[kf], s[an], 0, 0, 0);
            }
            __builtin_amdgcn_s_setprio(0);
            const bool need_mask = (kv0 + 63 > qw);
            const int qg = qw + (lane & 15);
            const int kbase = kv0 + ((lane >> 4) << 2);
            float p[4][4];
            float mx = -3e38f;
#pragma unroll
            for (int an = 0; an < 4; ++an)
#pragma unroll
                for (int i = 0; i < 4; ++i) {
                    float v = s[an][i];
                    if (need_mask && (kbase + an * 16 + i > qg)) v = -3e38f;
                    p[an][i] = v;
                    mx = fmaxf(mx, v);
                }
            mx = fmaxf(mx, __shfl_xor(mx, 16));
            mx = fmaxf(mx, __shfl_xor(mx, 32));
            // defer-max (T13): only rescale when max grew by > 8 (log2 units)
            if (!__all(mx <= mrun + 8.0f)) {
                const float mnew = fmaxf(mrun, mx);
                const float fsc = __builtin_amdgcn_exp2f(mrun - mnew);
                lrun *= fsc;
#pragma unroll
                for (int dn = 0; dn < 4; ++dn) o[dn] *= fsc;
                mrun = mnew;
            }
            float rs = 0.0f;
#pragma unroll
            for (int an = 0; an < 4; ++an)
#pragma unroll
                for (int i = 0; i < 4; ++i) {
                    p[an][i] = __builtin_amdgcn_exp2f(p[an][i] - mrun);
                    rs += p[an][i];
                }
            rs += __shfl_xor(rs, 16);
            rs += __shfl_xor(rs, 32);
            lrun += rs;
            // write P[q][kv] packed (4x ds_write_b64), swizzled
            const int ql = lane & 15;
            char* pb = (char*)Ps[wid] + ql * 128;
            const int xr = (ql & 7) << 4;
            const int gb = (lane >> 4) << 3;
#pragma unroll
            for (int an = 0; an < 4; ++an) {
                bf16x4v pk;
                pk[0] = (__bf16)p[an][0]; pk[1] = (__bf16)p[an][1];
                pk[2] = (__bf16)p[an][2]; pk[3] = (__bf16)p[an][3];
                *(bf16x4v*)(pb + ((an * 32 + gb) ^ xr)) = pk;
            }
            // PV: O^T += V^T * P^T
            __builtin_amdgcn_s_setprio(1);
#pragma unroll
            for (int kf = 0; kf < 2; ++kf) {
                bf16x8 vf[4], pf;
#pragma unroll
                for (int dn = 0; dn < 4; ++dn) {
                    const int r = dn * 16 + (lane & 15);
                    vf[dn] = *(const bf16x8*)((const char*)Vs[cur] + r * 128 + ((kf * 64 + (lane >> 4) * 16) ^ ((r & 7) << 4)));
                }
                {
                    const int qlr = lane & 15;
                    pf = *(const bf16x8*)((const char*)Ps[wid] + qlr * 128 + ((kf * 64 + (lane >> 4) * 16) ^ ((qlr & 7) << 4)));
                }
#pragma unroll
                for (int dn = 0; dn < 4; ++dn)
                    o[dn] = __builtin_amdgcn_mfma_f32_16x16x32_bf16(vf[dn], pf, o[dn], 0, 0, 0);
            }
            __builtin_amdgcn_s_setprio(0);
        }
        __syncthreads();
    }

    {
        const float inv = 1.0f / lrun;
        const int qg = qw + (lane & 15);
        unsigned short* yrow = yb + (size_t)(b * SEQ + qg) * CDIM + h * 64;
#pragma unroll
        for (int dn = 0; dn < 4; ++dn) {
            const int d = dn * 16 + ((lane >> 4) << 2);
            bf16x4v pk;
            pk[0] = (__bf16)(o[dn][0] * inv);
            pk[1] = (__bf16)(o[dn][1] * inv);
            pk[2] = (__bf16)(o[dn][2] * inv);
            pk[3] = (__bf16)(o[dn][3] * inv);
            *(bf16x4v*)(yrow + d) = pk;
        }
    }
}

// ---------------- host ----------------

extern "C" void kernel_launch(void* const* d_in, const int* in_sizes, int n_in,
                              void* d_out, int out_size, void* d_ws, size_t ws_size,
                              hipStream_t stream) {
    (void)in_sizes; (void)n_in; (void)out_size; (void)ws_size;
    const float* x  = (const float*)d_in[0];
    const float* Wq = (const float*)d_in[1];
    const float* bq = (const float*)d_in[2];
    const float* Wk = (const float*)d_in[3];
    const float* bk = (const float*)d_in[4];
    const float* Wv = (const float*)d_in[5];
    const float* bv = (const float*)d_in[6];
    const float* Wp = (const float*)d_in[7];
    const float* bp = (const float*)d_in[8];
    float* out = (float*)d_out;

    char* ws = (char*)d_ws;
    size_t off = 0;
    auto take = [&](size_t bytes) -> char* {
        char* p = ws + off;
        off = (off + bytes + 255) & ~(size_t)255;
        return p;
    };
    float2* cstab = (float2*)take((size_t)SEQ * 32 * 8);
    unsigned short* xb   = (unsigned short*)take((size_t)4096 * 1024 * 2);
    unsigned short* wqkv = (unsigned short*)take((size_t)3 * 1024 * 1024 * 2);
    unsigned short* wpb  = (unsigned short*)take((size_t)1024 * 1024 * 2);
    unsigned short* qbuf = (unsigned short*)take((size_t)32 * SEQ * HDIM * 2);
    unsigned short* kbuf = (unsigned short*)take((size_t)32 * SEQ * HDIM * 2);
    unsigned short* vtb  = (unsigned short*)take((size_t)32 * HDIM * SEQ * 2);
    unsigned short* yb   = (unsigned short*)take((size_t)4096 * 1024 * 2);

    rope_kernel<<<256, 256, 0, stream>>>(cstab);
    cvt_kernel<<<4096, 256, 0, stream>>>(x, xb, 1048576);
    cvtw_kernel<<<4096, 256, 0, stream>>>(Wq, Wk, Wv, Wp, wqkv, wpb);

    dim3 g0(24, 32);
    gemm_bt<0><<<g0, 256, 0, stream>>>(xb, wqkv, bq, bk, bv, qbuf, kbuf, vtb, nullptr, cstab);
    dim3 g1(32, 32);
    attn_kernel<<<g1, 256, 0, stream>>>(qbuf, kbuf, vtb, yb);
    dim3 g2(8, 32);
    gemm_bt<1><<<g2, 256, 0, stream>>>(yb, wpb, bp, nullptr, nullptr, nullptr, nullptr, nullptr, out, cstab);
}